// Round 4
// baseline (122.741 us; speedup 1.0000x reference)
//
#include <hip/hip_runtime.h>
#include <math.h>

#define SZ 256
#define KNN 4
#define NUM_CHANNELS 8
#define R 6                  // window radius (13x13); exact iff 4th d2 < 49
#define WROWS (2 * R + 1)    // 13
#define RSTRIDE 6            // LDS row: [zero pad][4 words][zero pad]

typedef unsigned long long u64;
typedef unsigned int u32;

// Branchless insert into ascending sorted 4 (u32 keys).
// key = (d2 << 16) | flat_idx, d2 < 128 in-window -> fits 23 bits.
// Matches jax.lax.top_k ordering incl. lower-index tie-break.
__device__ __forceinline__ void ins4(u32 key, u32& k0, u32& k1,
                                     u32& k2, u32& k3) {
    u32 m;
    m = (k2 > key) ? k2 : key;  k3 = (k3 < m) ? k3 : m;   // old k2
    m = (k1 > key) ? k1 : key;  k2 = (k2 < m) ? k2 : m;   // old k1
    m = (k0 > key) ? k0 : key;  k1 = (k1 < m) ? k1 : m;   // old k0
    k0 = (k0 < key) ? k0 : key;
}

__device__ __forceinline__ void ins4_64(u64 key, u64& k0, u64& k1,
                                        u64& k2, u64& k3) {
    if (key < k3) {
        u64 m;
        m = (k2 > key) ? k2 : key;  k3 = (k3 < m) ? k3 : m;
        m = (k1 > key) ? k1 : key;  k2 = (k2 < m) ? k2 : m;
        m = (k0 > key) ? k0 : key;  k1 = (k1 < m) ? k1 : m;
        k0 = (k0 < key) ? k0 : key;
    }
}

__global__ __launch_bounds__(256) void knn_fill(
    const float* __restrict__ img,
    const int*   __restrict__ lut,
    float*       __restrict__ out)
{
    __shared__ u64 win[WROWS * RSTRIDE];   // 624 B padded bitmap window

    const int x    = threadIdx.x;
    const int y    = blockIdx.x;           // block-uniform -> uniform row loop
    const int ch   = blockIdx.y;
    const int c    = ch + 1;
    const int lane = x & 63;
    const int w64  = x >> 6;

    // Zero pads + OOB rows, then build window bitmap via ballots.
    if (threadIdx.x < WROWS * RSTRIDE) win[threadIdx.x] = 0;
    __syncthreads();
    #pragma unroll
    for (int rr = 0; rr < WROWS; ++rr) {
        const int yy = y - R + rr;
        int v = 0;
        if (yy >= 0 && yy < SZ) v = lut[yy * SZ + x];
        const u64 bal = __ballot(v == c);
        if (lane == 0) win[rr * RSTRIDE + 1 + w64] = bal;
    }
    __syncthreads();

    const int pix = y * SZ + x;
    float* outc = out + (size_t)ch * (SZ * SZ);

    if ((win[R * RSTRIDE + 1 + (x >> 6)] >> (x & 63)) & 1ull) {
        outc[pix] = img[pix];
        return;
    }

    u32 k0 = ~0u, k1 = ~0u, k2 = ~0u, k3 = ~0u;

    const int base = x - R + 64;    // bit offset into padded row
    const int wrd  = base >> 6;     // 0..4
    const int sh   = base & 63;

    #pragma unroll
    for (int rr = 0; rr < WROWS; ++rr) {
        const u64 lo = win[rr * RSTRIDE + wrd];
        const u64 hi = win[rr * RSTRIDE + wrd + 1];
        u32 w = (u32)((u64)(((((unsigned __int128)hi) << 64) | lo) >> sh))
                & ((1u << WROWS) - 1);
        const int dy  = rr - R;
        const int dy2 = dy * dy;                 // uniform per row
        const int rowx = (y + dy) * SZ + x;      // idx of (row, this x)
        while (w) {
            const int b = __builtin_ctz(w);
            w &= w - 1;
            const int dx  = b - R;
            const u32 d2  = (u32)(dy2 + dx * dx);      // <= 72
            const u32 key = (d2 << 16) | (u32)(rowx + dx);
            ins4(key, k0, k1, k2, k3);
        }
    }

    u64 ks[KNN];
    // Exactness: outside window Chebyshev >= R+1 -> d2 >= 49. Strict '<'
    // so equal-d2 outside ties (lower idx could win) trigger the fallback.
    if ((k3 >> 16) < (u32)((R + 1) * (R + 1))) {
        ks[0] = k0; ks[1] = k1; ks[2] = k2; ks[3] = k3;  // same bit format
    } else {
        // Rare exact fallback (~1e-5/pixel): adaptive ring scan over lut.
        u64 q0 = ~0ull, q1 = ~0ull, q2 = ~0ull, q3 = ~0ull;
        for (int ady = 0; ady < SZ; ++ady) {
            const u64 cur = q3 >> 16;
            const u64 a2  = (u64)(ady * ady);
            if (a2 > cur) break;
            int Rx;
            const u64 bound = cur - a2;
            if (bound >= 65025ull) Rx = SZ - 1;
            else Rx = (int)sqrtf((float)bound) + 1;
            int xs = x - Rx; if (xs < 0) xs = 0;
            int xe = x + Rx; if (xe > SZ - 1) xe = SZ - 1;
            for (int s = 0; s < 2; ++s) {
                if (s && ady == 0) continue;
                const int yy = s ? y + ady : y - ady;
                if (yy < 0 || yy > SZ - 1) continue;
                const int rb = yy * SZ;
                for (int xx = xs; xx <= xe; ++xx) {
                    if (lut[rb + xx] == c) {
                        const int dxx = xx - x;
                        const u64 d2 = a2 + (u64)(dxx * dxx);
                        ins4_64((d2 << 16) | (u32)(rb + xx), q0, q1, q2, q3);
                    }
                }
            }
        }
        ks[0] = q0; ks[1] = q1; ks[2] = q2; ks[3] = q3;
    }

    // Weighted sum in top_k order (ascending (d2, idx)), matching reference.
    float num = 0.0f, den = 0.0f;
    #pragma unroll
    for (int i = 0; i < KNN; ++i) {
        const int idx = (int)(ks[i] & 0xFFFFull);
        const int d2i = (int)(ks[i] >> 16);
        const float dist = sqrtf((float)d2i * (1.0f / 65536.0f));
        num += img[idx] * dist;
        den += dist;
    }
    outc[pix] = num / den;
}

extern "C" void kernel_launch(void* const* d_in, const int* in_sizes, int n_in,
                              void* d_out, int out_size, void* d_ws, size_t ws_size,
                              hipStream_t stream) {
    const float* img = (const float*)d_in[0];   // coded: [1,1,256,256] f32
    const int*   lut = (const int*)d_in[1];     // lookup_table: [256,256] i32
    float*       out = (float*)d_out;           // [1,8,256,256] f32

    knn_fill<<<dim3(SZ, NUM_CHANNELS), dim3(256), 0, stream>>>(img, lut, out);
}

// Round 5
// 74.121 us; speedup vs baseline: 1.6560x; 1.6560x over previous
//
#include <hip/hip_runtime.h>
#include <math.h>

#define SZ 256
#define KNN 4
#define NUM_CHANNELS 8
#define R 7                  // window radius (15x15); exact iff 4th d2 < 64
#define WROWS (2 * R + 1)    // 15
#define RSTRIDE 6            // LDS row: [zero pad][4 words][zero pad]

typedef unsigned long long u64;
typedef unsigned int u32;

// Branchless insert into ascending sorted 4 (u32 keys).
// key = (d2 << 16) | flat_idx, in-window d2 <= 98 -> fits easily.
// Matches jax.lax.top_k ordering incl. lower-index tie-break.
__device__ __forceinline__ void ins4(u32 key, u32& k0, u32& k1,
                                     u32& k2, u32& k3) {
    u32 m;
    m = (k2 > key) ? k2 : key;  k3 = (k3 < m) ? k3 : m;   // old k2
    m = (k1 > key) ? k1 : key;  k2 = (k2 < m) ? k2 : m;   // old k1
    m = (k0 > key) ? k0 : key;  k1 = (k1 < m) ? k1 : m;   // old k0
    k0 = (k0 < key) ? k0 : key;
}

__device__ __forceinline__ void ins4_64(u64 key, u64& k0, u64& k1,
                                        u64& k2, u64& k3) {
    if (key < k3) {
        u64 m;
        m = (k2 > key) ? k2 : key;  k3 = (k3 < m) ? k3 : m;
        m = (k1 > key) ? k1 : key;  k2 = (k2 < m) ? k2 : m;
        m = (k0 > key) ? k0 : key;  k1 = (k1 < m) ? k1 : m;
        k0 = (k0 < key) ? k0 : key;
    }
}

// Pass 1: per-channel occupancy bitmaps via wave ballot.
// bm layout: u64[NUM_CHANNELS][SZ][4]; word j covers x in [j*64, j*64+64).
__global__ __launch_bounds__(256) void build_bitmaps(
    const int* __restrict__ lut,
    u64* __restrict__ bm)
{
    const int y = blockIdx.x;
    const int x = threadIdx.x;
    const int v = lut[y * SZ + x];
    const int lane = x & 63;
    const int w64 = x >> 6;
    #pragma unroll
    for (int c = 1; c <= NUM_CHANNELS; ++c) {
        u64 bal = __ballot(v == c);
        if (lane == 0) bm[(size_t)(c - 1) * (SZ * 4) + y * 4 + w64] = bal;
    }
}

// Pass 2: wave-uniform fixed-window scan; rare bitmap-based exact fallback.
__global__ __launch_bounds__(256) void knn_fill(
    const float* __restrict__ img,
    const u64*   __restrict__ bm,
    float*       __restrict__ out)
{
    __shared__ u64 win[WROWS * RSTRIDE];   // 720 B padded window bitmap

    const int x  = threadIdx.x;
    const int y  = blockIdx.x;             // block-uniform -> uniform row loop
    const int ch = blockIdx.y;
    const u64* bmc = bm + (size_t)ch * (SZ * 4);

    // Stage only the 15 window rows (90 words), zero-padded.
    if (threadIdx.x < WROWS * RSTRIDE) {
        const int rr = threadIdx.x / RSTRIDE;
        const int j  = threadIdx.x - rr * RSTRIDE;
        const int yy = y - R + rr;
        u64 v = 0;
        if (j >= 1 && j <= 4 && yy >= 0 && yy < SZ) v = bmc[yy * 4 + (j - 1)];
        win[threadIdx.x] = v;
    }
    __syncthreads();

    const int pix = y * SZ + x;
    float* outc = out + (size_t)ch * (SZ * SZ);

    if ((win[R * RSTRIDE + 1 + (x >> 6)] >> (x & 63)) & 1ull) {
        outc[pix] = img[pix];
        return;
    }

    u32 k0 = ~0u, k1 = ~0u, k2 = ~0u, k3 = ~0u;

    const int base = x - R + 64;    // bit offset into padded row
    const int wrd  = base >> 6;     // 0..4
    const int sh   = base & 63;

    #pragma unroll
    for (int rr = 0; rr < WROWS; ++rr) {
        const u64 lo = win[rr * RSTRIDE + wrd];
        const u64 hi = win[rr * RSTRIDE + wrd + 1];
        u32 w = (u32)((u64)(((((unsigned __int128)hi) << 64) | lo) >> sh))
                & ((1u << WROWS) - 1);
        const int dy   = rr - R;
        const int dy2  = dy * dy;
        const int rowx = (y + dy) * SZ + x;   // flat idx of (row, this x)
        while (w) {
            const int b = __builtin_ctz(w);
            w &= w - 1;
            const int dx  = b - R;
            const u32 d2  = (u32)(dy2 + dx * dx);        // <= 98
            const u32 key = (d2 << 16) | (u32)(rowx + dx);
            ins4(key, k0, k1, k2, k3);
        }
    }

    u64 ks[KNN];
    const u32 in_d2 = k3 >> 16;
    // Exactness: outside window Chebyshev >= R+1 -> d2 >= 64. Strict '<'
    // so equal-d2 outside ties (lower idx could win) trigger the fallback.
    if (in_d2 < (u32)((R + 1) * (R + 1))) {
        ks[0] = k0; ks[1] = k1; ks[2] = k2; ks[3] = k3;  // same bit format
    } else {
        // Rare exact fallback: adaptive bitmap ring scan, pruned by the
        // window's 4th-best d2 when available (valid upper bound on the
        // final 4th distance; '<=' semantics keep tie-breaks exact).
        const u64 cap = (in_d2 != 0xFFFFu) ? (u64)in_d2 : (~0ull >> 16);
        u64 q0 = ~0ull, q1 = ~0ull, q2 = ~0ull, q3 = ~0ull;
        for (int ady = 0; ady < SZ; ++ady) {
            u64 cur = q3 >> 16;
            if (cap < cur) cur = cap;
            const u64 a2 = (u64)(ady * ady);
            if (a2 > cur) break;          // keep a2 == cur (ties)
            int Rx;
            const u64 bound = cur - a2;
            if (bound >= 65025ull) Rx = SZ - 1;
            else Rx = (int)sqrtf((float)bound) + 1;   // conservative
            int xs = x - Rx; if (xs < 0) xs = 0;
            int xe = x + Rx; if (xe > SZ - 1) xe = SZ - 1;
            const int jxs = xs >> 6, jxe = xe >> 6;
            const u64 mlo = (~0ull) << (xs & 63);
            const u64 mhi = (~0ull) >> (63 - (xe & 63));
            for (int s = 0; s < 2; ++s) {
                if (s && ady == 0) continue;
                const int yy = s ? y + ady : y - ady;
                if (yy < 0 || yy > SZ - 1) continue;
                const int rb = yy * SZ;
                for (int j = jxs; j <= jxe; ++j) {
                    u64 w = bmc[yy * 4 + j];
                    if (j == jxs) w &= mlo;
                    if (j == jxe) w &= mhi;
                    while (w) {
                        const int b = __builtin_ctzll(w);
                        w &= w - 1;
                        const int xx = (j << 6) + b;
                        const int dxx = xx - x;
                        const u64 d2 = a2 + (u64)(dxx * dxx);
                        ins4_64((d2 << 16) | (u32)(rb + xx), q0, q1, q2, q3);
                    }
                }
            }
        }
        ks[0] = q0; ks[1] = q1; ks[2] = q2; ks[3] = q3;
    }

    // Weighted sum in top_k order (ascending (d2, idx)), matching reference.
    float num = 0.0f, den = 0.0f;
    #pragma unroll
    for (int i = 0; i < KNN; ++i) {
        const int idx = (int)(ks[i] & 0xFFFFull);
        const int d2i = (int)(ks[i] >> 16);
        const float dist = sqrtf((float)d2i * (1.0f / 65536.0f));
        num += img[idx] * dist;
        den += dist;
    }
    outc[pix] = num / den;
}

extern "C" void kernel_launch(void* const* d_in, const int* in_sizes, int n_in,
                              void* d_out, int out_size, void* d_ws, size_t ws_size,
                              hipStream_t stream) {
    const float* img = (const float*)d_in[0];   // coded: [1,1,256,256] f32
    const int*   lut = (const int*)d_in[1];     // lookup_table: [256,256] i32
    float*       out = (float*)d_out;           // [1,8,256,256] f32
    u64*         bm  = (u64*)d_ws;              // 64 KB bitmaps

    build_bitmaps<<<dim3(SZ), dim3(256), 0, stream>>>(lut, bm);
    knn_fill<<<dim3(SZ, NUM_CHANNELS), dim3(256), 0, stream>>>(img, bm, out);
}